// Round 1
// baseline (188.719 us; speedup 1.0000x reference)
//
#include <hip/hip_runtime.h>
#include <math.h>

namespace {
constexpr int Bc = 8, Sc = 500, Vc = 100, Fc = 5, Kc = 12, FKc = 60;
constexpr float EPSc = 1e-5f;
}

// Precompute negated quadratic coefficients so that
// -(x-mu)^2/(sig^2+EPS) = (n1*x + n2)*x + n3  (2 FMAs)
__device__ __forceinline__ void gauss_consts(
    const float* __restrict__ mu_rho, const float* __restrict__ sigma_rho,
    const float* __restrict__ mu_theta, const float* __restrict__ sigma_theta,
    int fk,
    float& nr1, float& nr2, float& nr3,
    float& nt1, float& nt2, float& nt3)
{
    float mr = mu_rho[fk],  sr = sigma_rho[fk];
    float mt = mu_theta[fk], st = sigma_theta[fk];
    float isr = 1.0f / (sr * sr + EPSc);
    float ist = 1.0f / (st * st + EPSc);
    nr1 = -isr; nr2 = 2.0f * isr * mr; nr3 = -(isr * mr) * mr;
    nt1 = -ist; nt2 = 2.0f * ist * mt; nt3 = -(ist * mt) * mt;
}

// Kernel 1: inv_denom[(b*V+v)*60 + fk] = 1 / (sum_s g[b,f,s,v,k] + EPS)
// One block per (b,v); thread fk owns one gaussian; serial loop over s.
__global__ __launch_bounds__(64) void k_denom(
    const float* __restrict__ rho, const float* __restrict__ theta,
    const float* __restrict__ mask,
    const float* __restrict__ mu_rho, const float* __restrict__ sigma_rho,
    const float* __restrict__ mu_theta, const float* __restrict__ sigma_theta,
    float* __restrict__ inv_denom)
{
    const int bv = blockIdx.x;           // 0 .. B*V-1
    const int b = bv / Vc, v = bv % Vc;
    const int lane = threadIdx.x;        // 0..63
    const int fk = lane < FKc ? lane : FKc - 1;

    float nr1, nr2, nr3, nt1, nt2, nt3;
    gauss_consts(mu_rho, sigma_rho, mu_theta, sigma_theta, fk,
                 nr1, nr2, nr3, nt1, nt2, nt3);

    const size_t base = (size_t)b * Sc * Vc + v;
    const float* rp = rho + base;
    const float* tp = theta + base;
    const float* mp = mask + base;

    float acc = 0.0f;
#pragma unroll 4
    for (int s = 0; s < Sc; ++s) {
        float r = rp[(size_t)s * Vc];   // wave-uniform address
        float t = tp[(size_t)s * Vc];
        float m = mp[(size_t)s * Vc];
        float ar = __fmaf_rn(__fmaf_rn(nr1, r, nr2), r, nr3);
        float at = __fmaf_rn(__fmaf_rn(nt1, t, nt2), t, nt3 + ar);
        acc = __fmaf_rn(__expf(at), m, acc);
    }
    if (lane < FKc)
        inv_denom[(size_t)bv * FKc + lane] = 1.0f / (acc + EPSc);
}

// Kernel 2: one block per (b,s). Computes desc[60] = sum_v g_norm * feat,
// then conv(KxK per f) + relu, MLP 60->12->5->3, softmax, writes 3 floats.
__global__ __launch_bounds__(256) void k_main(
    const float* __restrict__ feat, const float* __restrict__ rho,
    const float* __restrict__ theta, const float* __restrict__ mask,
    const float* __restrict__ mu_rho, const float* __restrict__ sigma_rho,
    const float* __restrict__ mu_theta, const float* __restrict__ sigma_theta,
    const float* __restrict__ Wc, const float* __restrict__ bc,
    const float* __restrict__ W2, const float* __restrict__ b2,
    const float* __restrict__ W3, const float* __restrict__ b3,
    const float* __restrict__ W4, const float* __restrict__ b4,
    const float* __restrict__ inv_denom,
    float* __restrict__ out)
{
    const int bs = blockIdx.x;           // b*S + s
    const int b = bs / Sc;
    const int tid = threadIdx.x;
    const int lane = tid & 63;           // fk lane
    const int vg = tid >> 6;             // 0..3, 25 vertices each
    const int fk = lane < FKc ? lane : FKc - 1;
    const int f = fk / Kc;

    __shared__ float lds_red[4][FKc];
    __shared__ float lds_desc[FKc];
    __shared__ float lds_gd[FKc];
    __shared__ float lds_h1[Kc];
    __shared__ float lds_h2[Fc];
    __shared__ float lds_logit[3];

    float nr1, nr2, nr3, nt1, nt2, nt3;
    gauss_consts(mu_rho, sigma_rho, mu_theta, sigma_theta, fk,
                 nr1, nr2, nr3, nt1, nt2, nt3);

    const size_t base_sv = (size_t)bs * Vc;     // (b*S+s)*V
    const size_t base_bv = (size_t)b * Vc;      // b*V

    float acc = 0.0f;
    const int v0 = vg * 25;
#pragma unroll 5
    for (int v = v0; v < v0 + 25; ++v) {
        float r = rho[base_sv + v];             // wave-uniform
        float t = theta[base_sv + v];
        float m = mask[base_sv + v];
        float fv = feat[(base_sv + v) * Fc + f];
        float id = inv_denom[(base_bv + v) * FKc + fk];  // coalesced
        float ar = __fmaf_rn(__fmaf_rn(nr1, r, nr2), r, nr3);
        float at = __fmaf_rn(__fmaf_rn(nt1, t, nt2), t, nt3 + ar);
        float g = __expf(at) * m * id;
        acc = __fmaf_rn(g, fv, acc);
    }
    if (lane < FKc) lds_red[vg][lane] = acc;
    __syncthreads();

    // reduce 4 v-groups -> desc
    if (tid < FKc) {
        lds_desc[tid] = lds_red[0][tid] + lds_red[1][tid] +
                        lds_red[2][tid] + lds_red[3][tid];
    }
    __syncthreads();

    // conv: per (f,j): relu(sum_k desc[f,k] * Wc[f,k,j] + bc[f,j])
    if (tid < FKc) {
        const int ff = tid / Kc, j = tid % Kc;
        float sum = bc[tid];
#pragma unroll
        for (int k = 0; k < Kc; ++k)
            sum = __fmaf_rn(lds_desc[ff * Kc + k], Wc[ff * Kc * Kc + k * Kc + j], sum);
        lds_gd[tid] = fmaxf(sum, 0.0f);
    }
    __syncthreads();

    // h1 = relu(gd @ W2 + b2)  (60 -> 12)
    if (tid < Kc) {
        float sum = b2[tid];
#pragma unroll
        for (int i = 0; i < FKc; ++i)
            sum = __fmaf_rn(lds_gd[i], W2[i * Kc + tid], sum);
        lds_h1[tid] = fmaxf(sum, 0.0f);
    }
    __syncthreads();

    // h2 = relu(h1 @ W3 + b3)  (12 -> 5)
    if (tid < Fc) {
        float sum = b3[tid];
#pragma unroll
        for (int i = 0; i < Kc; ++i)
            sum = __fmaf_rn(lds_h1[i], W3[i * Fc + tid], sum);
        lds_h2[tid] = fmaxf(sum, 0.0f);
    }
    __syncthreads();

    // logits = h2 @ W4 + b4  (5 -> 3)
    if (tid < 3) {
        float sum = b4[tid];
#pragma unroll
        for (int i = 0; i < Fc; ++i)
            sum = __fmaf_rn(lds_h2[i], W4[i * 3 + tid], sum);
        lds_logit[tid] = sum;
    }
    __syncthreads();

    // softmax over 3 logits, write out
    if (tid == 0) {
        float l0 = lds_logit[0], l1 = lds_logit[1], l2 = lds_logit[2];
        float mx = fmaxf(l0, fmaxf(l1, l2));
        float e0 = __expf(l0 - mx), e1 = __expf(l1 - mx), e2 = __expf(l2 - mx);
        float inv = 1.0f / (e0 + e1 + e2);
        out[(size_t)bs * 3 + 0] = e0 * inv;
        out[(size_t)bs * 3 + 1] = e1 * inv;
        out[(size_t)bs * 3 + 2] = e2 * inv;
    }
}

extern "C" void kernel_launch(void* const* d_in, const int* in_sizes, int n_in,
                              void* d_out, int out_size, void* d_ws, size_t ws_size,
                              hipStream_t stream) {
    const float* feat     = (const float*)d_in[0];
    const float* rho      = (const float*)d_in[1];
    const float* theta    = (const float*)d_in[2];
    const float* mask     = (const float*)d_in[3];
    const float* mu_rho   = (const float*)d_in[4];
    const float* sig_rho  = (const float*)d_in[5];
    const float* mu_theta = (const float*)d_in[6];
    const float* sig_th   = (const float*)d_in[7];
    const float* Wc       = (const float*)d_in[8];
    const float* bc       = (const float*)d_in[9];
    const float* W2       = (const float*)d_in[10];
    const float* b2       = (const float*)d_in[11];
    const float* W3       = (const float*)d_in[12];
    const float* b3       = (const float*)d_in[13];
    const float* W4       = (const float*)d_in[14];
    const float* b4       = (const float*)d_in[15];

    float* inv_denom = (float*)d_ws;  // B*V*60 floats = 192 KB

    k_denom<<<Bc * Vc, 64, 0, stream>>>(
        rho, theta, mask, mu_rho, sig_rho, mu_theta, sig_th, inv_denom);

    k_main<<<Bc * Sc, 256, 0, stream>>>(
        feat, rho, theta, mask, mu_rho, sig_rho, mu_theta, sig_th,
        Wc, bc, W2, b2, W3, b3, W4, b4, inv_denom, (float*)d_out);
}

// Round 2
// 166.186 us; speedup vs baseline: 1.1356x; 1.1356x over previous
//
#include <hip/hip_runtime.h>
#include <math.h>

namespace {
constexpr int Bc = 8, Sc = 500, Vc = 100, Fc = 5, Kc = 12, FKc = 60;
constexpr int BV = Bc * Vc;          // 800
constexpr int NDEN = BV * FKc;       // 48000
constexpr float EPSc = 1e-5f;
}

// -(x-mu)^2/(sig^2+EPS) = (n1*x + n2)*x + n3  (2 FMAs)
__device__ __forceinline__ void gauss_consts(
    const float* __restrict__ mu_rho, const float* __restrict__ sigma_rho,
    const float* __restrict__ mu_theta, const float* __restrict__ sigma_theta,
    int fk,
    float& nr1, float& nr2, float& nr3,
    float& nt1, float& nt2, float& nt3)
{
    float mr = mu_rho[fk],  sr = sigma_rho[fk];
    float mt = mu_theta[fk], st = sigma_theta[fk];
    float isr = 1.0f / (sr * sr + EPSc);
    float ist = 1.0f / (st * st + EPSc);
    nr1 = -isr; nr2 = 2.0f * isr * mr; nr3 = -(isr * mr) * mr;
    nt1 = -ist; nt2 = 2.0f * ist * mt; nt3 = -(ist * mt) * mt;
}

// Partial denominator: grid = (B*V, SCH). Block (bv, c) sums g over its
// s-chunk for all 60 (f,k); writes partial[c][bv][fk].
__global__ __launch_bounds__(64) void k_denom_partial(
    const float* __restrict__ rho, const float* __restrict__ theta,
    const float* __restrict__ mask,
    const float* __restrict__ mu_rho, const float* __restrict__ sigma_rho,
    const float* __restrict__ mu_theta, const float* __restrict__ sigma_theta,
    float* __restrict__ partial)
{
    const int bv = blockIdx.x;
    const int c  = blockIdx.y;
    const int SCH = gridDim.y;
    const int b = bv / Vc, v = bv % Vc;
    const int lane = threadIdx.x;
    const int fk = lane < FKc ? lane : FKc - 1;

    float nr1, nr2, nr3, nt1, nt2, nt3;
    gauss_consts(mu_rho, sigma_rho, mu_theta, sigma_theta, fk,
                 nr1, nr2, nr3, nt1, nt2, nt3);

    const int chunk = (Sc + SCH - 1) / SCH;
    const int s0 = c * chunk;
    const int s1 = min(Sc, s0 + chunk);

    const size_t base = (size_t)b * Sc * Vc + v;
    const float* rp = rho + base;
    const float* tp = theta + base;
    const float* mp = mask + base;

    float acc = 0.0f;
#pragma unroll 5
    for (int s = s0; s < s1; ++s) {
        float r = rp[(size_t)s * Vc];   // wave-uniform address (1 line)
        float t = tp[(size_t)s * Vc];
        float m = mp[(size_t)s * Vc];
        float ar = __fmaf_rn(__fmaf_rn(nr1, r, nr2), r, nr3);
        float at = __fmaf_rn(__fmaf_rn(nt1, t, nt2), t, nt3 + ar);
        acc = __fmaf_rn(__expf(at), m, acc);
    }
    if (lane < FKc)
        partial[(size_t)c * NDEN + (size_t)bv * FKc + lane] = acc;
}

// Sum the SCH chunks, invert: inv_denom[bv*60+fk] = 1/(sum + EPS)
__global__ __launch_bounds__(64) void k_inv(
    const float* __restrict__ partial, float* __restrict__ inv_denom, int SCH)
{
    const int bv = blockIdx.x;
    const int lane = threadIdx.x;
    if (lane >= FKc) return;
    float s = 0.0f;
    for (int c = 0; c < SCH; ++c)
        s += partial[(size_t)c * NDEN + (size_t)bv * FKc + lane];
    inv_denom[(size_t)bv * FKc + lane] = 1.0f / (s + EPSc);
}

// Main: one WAVE per (b,s). Lane fk computes desc[fk] over all 100 v,
// then the whole conv+MLP+softmax tail runs in-wave via LDS.
__global__ __launch_bounds__(64) void k_main(
    const float* __restrict__ feat, const float* __restrict__ rho,
    const float* __restrict__ theta, const float* __restrict__ mask,
    const float* __restrict__ mu_rho, const float* __restrict__ sigma_rho,
    const float* __restrict__ mu_theta, const float* __restrict__ sigma_theta,
    const float* __restrict__ Wc, const float* __restrict__ bc,
    const float* __restrict__ W2, const float* __restrict__ b2,
    const float* __restrict__ W3, const float* __restrict__ b3,
    const float* __restrict__ W4, const float* __restrict__ b4,
    const float* __restrict__ inv_denom,
    float* __restrict__ out)
{
    const int bs = blockIdx.x;           // b*S + s
    const int b = bs / Sc;
    const int lane = threadIdx.x;        // 0..63
    const int fk = lane < FKc ? lane : FKc - 1;
    const int f = fk / Kc;

    __shared__ float lds_feat[Vc * Fc];  // 500 floats, this block's feat row
    __shared__ float lds_desc[FKc];
    __shared__ float lds_gd[FKc];
    __shared__ float lds_h1[Kc];
    __shared__ float lds_h2[Fc];
    __shared__ float lds_logit[3];

    // stage feat row (coalesced)
    const float* frow = feat + (size_t)bs * Vc * Fc;
#pragma unroll
    for (int i = lane; i < Vc * Fc; i += 64)
        lds_feat[i] = frow[i];

    float nr1, nr2, nr3, nt1, nt2, nt3;
    gauss_consts(mu_rho, sigma_rho, mu_theta, sigma_theta, fk,
                 nr1, nr2, nr3, nt1, nt2, nt3);

    const size_t base_sv = (size_t)bs * Vc;     // (b*S+s)*V
    const size_t base_bv = (size_t)b * Vc;      // b*V
    const float4* r4 = (const float4*)(rho + base_sv);    // 400B-aligned
    const float4* t4 = (const float4*)(theta + base_sv);
    const float4* m4 = (const float4*)(mask + base_sv);

    __syncthreads();

    float acc = 0.0f;
    for (int vq = 0; vq < Vc / 4; ++vq) {
        float4 R = r4[vq], T = t4[vq], M = m4[vq];   // wave-uniform 16B
        const float rr[4] = {R.x, R.y, R.z, R.w};
        const float tt[4] = {T.x, T.y, T.z, T.w};
        const float mm[4] = {M.x, M.y, M.z, M.w};
#pragma unroll
        for (int u = 0; u < 4; ++u) {
            const int v = vq * 4 + u;
            float id = inv_denom[(base_bv + v) * FKc + fk];  // coalesced
            float fv = lds_feat[v * Fc + f];
            float ar = __fmaf_rn(__fmaf_rn(nr1, rr[u], nr2), rr[u], nr3);
            float at = __fmaf_rn(__fmaf_rn(nt1, tt[u], nt2), tt[u], nt3 + ar);
            float g = __expf(at) * mm[u] * id;
            acc = __fmaf_rn(g, fv, acc);
        }
    }
    if (lane < FKc) lds_desc[lane] = acc;
    __syncthreads();

    // conv per (f,j): relu(sum_k desc[f,k]*Wc[f,k,j] + bc[f,j])
    if (lane < FKc) {
        const int ff = lane / Kc, j = lane % Kc;
        float sum = bc[lane];
#pragma unroll
        for (int k = 0; k < Kc; ++k)
            sum = __fmaf_rn(lds_desc[ff * Kc + k],
                            Wc[ff * Kc * Kc + k * Kc + j], sum);
        lds_gd[lane] = fmaxf(sum, 0.0f);
    }
    __syncthreads();

    // h1 = relu(gd @ W2 + b2)  (60 -> 12)
    if (lane < Kc) {
        float sum = b2[lane];
#pragma unroll
        for (int i = 0; i < FKc; ++i)
            sum = __fmaf_rn(lds_gd[i], W2[i * Kc + lane], sum);
        lds_h1[lane] = fmaxf(sum, 0.0f);
    }
    __syncthreads();

    // h2 = relu(h1 @ W3 + b3)  (12 -> 5)
    if (lane < Fc) {
        float sum = b3[lane];
#pragma unroll
        for (int i = 0; i < Kc; ++i)
            sum = __fmaf_rn(lds_h1[i], W3[i * Fc + lane], sum);
        lds_h2[lane] = fmaxf(sum, 0.0f);
    }
    __syncthreads();

    // logits (5 -> 3)
    if (lane < 3) {
        float sum = b4[lane];
#pragma unroll
        for (int i = 0; i < Fc; ++i)
            sum = __fmaf_rn(lds_h2[i], W4[i * 3 + lane], sum);
        lds_logit[lane] = sum;
    }
    __syncthreads();

    if (lane == 0) {
        float l0 = lds_logit[0], l1 = lds_logit[1], l2 = lds_logit[2];
        float mx = fmaxf(l0, fmaxf(l1, l2));
        float e0 = __expf(l0 - mx), e1 = __expf(l1 - mx), e2 = __expf(l2 - mx);
        float inv = 1.0f / (e0 + e1 + e2);
        out[(size_t)bs * 3 + 0] = e0 * inv;
        out[(size_t)bs * 3 + 1] = e1 * inv;
        out[(size_t)bs * 3 + 2] = e2 * inv;
    }
}

extern "C" void kernel_launch(void* const* d_in, const int* in_sizes, int n_in,
                              void* d_out, int out_size, void* d_ws, size_t ws_size,
                              hipStream_t stream) {
    const float* feat     = (const float*)d_in[0];
    const float* rho      = (const float*)d_in[1];
    const float* theta    = (const float*)d_in[2];
    const float* mask     = (const float*)d_in[3];
    const float* mu_rho   = (const float*)d_in[4];
    const float* sig_rho  = (const float*)d_in[5];
    const float* mu_theta = (const float*)d_in[6];
    const float* sig_th   = (const float*)d_in[7];
    const float* Wc       = (const float*)d_in[8];
    const float* bc       = (const float*)d_in[9];
    const float* W2       = (const float*)d_in[10];
    const float* b2       = (const float*)d_in[11];
    const float* W3       = (const float*)d_in[12];
    const float* b3       = (const float*)d_in[13];
    const float* W4       = (const float*)d_in[14];
    const float* b4       = (const float*)d_in[15];

    // workspace: inv_denom (48000 f) then partials (SCH * 48000 f)
    float* inv_denom = (float*)d_ws;
    size_t inv_bytes = (size_t)NDEN * 4;
    size_t rem = ws_size > inv_bytes ? ws_size - inv_bytes : 0;
    int SCH = (int)(rem / inv_bytes);
    if (SCH > 20) SCH = 20;
    float* partial;
    if (SCH < 1) { SCH = 1; partial = inv_denom; }   // in-place fallback
    else partial = inv_denom + NDEN;

    k_denom_partial<<<dim3(BV, SCH), 64, 0, stream>>>(
        rho, theta, mask, mu_rho, sig_rho, mu_theta, sig_th, partial);

    k_inv<<<BV, 64, 0, stream>>>(partial, inv_denom, SCH);

    k_main<<<Bc * Sc, 64, 0, stream>>>(
        feat, rho, theta, mask, mu_rho, sig_rho, mu_theta, sig_th,
        Wc, bc, W2, b2, W3, b3, W4, b4, inv_denom, (float*)d_out);
}

// Round 3
// 140.635 us; speedup vs baseline: 1.3419x; 1.1817x over previous
//
#include <hip/hip_runtime.h>
#include <math.h>

namespace {
constexpr int Bc = 8, Sc = 500, Vc = 100, Fc = 5, Kc = 12, FKc = 60;
constexpr int BV = Bc * Vc;          // 800
constexpr int NDEN = BV * FKc;       // 48000 (= B * V * 60)
constexpr int VG = 25;               // v's per wave in k_denom / k_main
constexpr float EPSc = 1e-5f;
}

// -(x-mu)^2/(sig^2+EPS) = (n1*x + n2)*x + n3  (2 FMAs)
__device__ __forceinline__ void gauss_consts(
    const float* __restrict__ mu_rho, const float* __restrict__ sigma_rho,
    const float* __restrict__ mu_theta, const float* __restrict__ sigma_theta,
    int fk,
    float& nr1, float& nr2, float& nr3,
    float& nt1, float& nt2, float& nt3)
{
    float mr = mu_rho[fk],  sr = sigma_rho[fk];
    float mt = mu_theta[fk], st = sigma_theta[fk];
    float isr = 1.0f / (sr * sr + EPSc);
    float ist = 1.0f / (st * st + EPSc);
    nr1 = -isr; nr2 = 2.0f * isr * mr; nr3 = -(isr * mr) * mr;
    nt1 = -ist; nt2 = 2.0f * ist * mt; nt3 = -(ist * mt) * mt;
}

// Denominator partials. Grid (SCH, B, 4): block = (s-chunk c, batch b,
// v-group wg of 25 v's), 1 wave. Lane = fk; 25 register accumulators,
// contiguous (s,v) walk -> full cache-line utilization.
// partial[c][b][v][fk] flat = c*NDEN + (b*V+v)*60 + fk
__global__ __launch_bounds__(64) void k_denom_partial(
    const float* __restrict__ rho, const float* __restrict__ theta,
    const float* __restrict__ mask,
    const float* __restrict__ mu_rho, const float* __restrict__ sigma_rho,
    const float* __restrict__ mu_theta, const float* __restrict__ sigma_theta,
    float* __restrict__ partial, int chunk)
{
    const int c  = blockIdx.x;
    const int b  = blockIdx.y;
    const int wg = blockIdx.z;           // 0..3
    const int lane = threadIdx.x;
    const int fk = lane < FKc ? lane : FKc - 1;
    const int v0 = wg * VG;

    float nr1, nr2, nr3, nt1, nt2, nt3;
    gauss_consts(mu_rho, sigma_rho, mu_theta, sigma_theta, fk,
                 nr1, nr2, nr3, nt1, nt2, nt3);

    const int s0 = c * chunk;
    const int s1 = min(Sc, s0 + chunk);

    float acc[VG];
#pragma unroll
    for (int i = 0; i < VG; ++i) acc[i] = 0.0f;

    const size_t base = (size_t)b * Sc * Vc + v0;
    for (int s = s0; s < s1; ++s) {
        const float* rp = rho   + base + (size_t)s * Vc;
        const float* tp = theta + base + (size_t)s * Vc;
        const float* mp = mask  + base + (size_t)s * Vc;
#pragma unroll
        for (int vi = 0; vi < VG; ++vi) {
            float r = rp[vi], t = tp[vi], m = mp[vi];   // wave-uniform, L1-hot
            float ar = __fmaf_rn(__fmaf_rn(nr1, r, nr2), r, nr3);
            float at = __fmaf_rn(__fmaf_rn(nt1, t, nt2), t, nt3 + ar);
            acc[vi] = __fmaf_rn(__expf(at), m, acc[vi]);
        }
    }

    float* pp = partial + (size_t)c * NDEN + ((size_t)b * Vc + v0) * FKc;
    if (lane < FKc) {
#pragma unroll
        for (int vi = 0; vi < VG; ++vi)
            pp[(size_t)vi * FKc + lane] = acc[vi];      // coalesced 240B
    }
}

// inv_denom[i] = 1/(sum_c partial[c][i] + EPS), i = (b*V+v)*60+fk
__global__ __launch_bounds__(256) void k_inv(
    const float* __restrict__ partial, float* __restrict__ inv_denom, int SCH)
{
    const int i = blockIdx.x * 256 + threadIdx.x;
    if (i >= NDEN) return;
    float s = 0.0f;
    for (int c = 0; c < SCH; ++c)
        s += partial[(size_t)c * NDEN + i];             // coalesced
    inv_denom[i] = 1.0f / (s + EPSc);
}

// Main: 256 threads (4 waves) per (b,s). inv_denom[b] (24KB) + feat row
// staged in LDS; wave w owns v in [25w, 25w+25); lane = fk. Tail in-block.
__global__ __launch_bounds__(256) void k_main(
    const float* __restrict__ feat, const float* __restrict__ rho,
    const float* __restrict__ theta, const float* __restrict__ mask,
    const float* __restrict__ mu_rho, const float* __restrict__ sigma_rho,
    const float* __restrict__ mu_theta, const float* __restrict__ sigma_theta,
    const float* __restrict__ Wc, const float* __restrict__ bc,
    const float* __restrict__ W2, const float* __restrict__ b2,
    const float* __restrict__ W3, const float* __restrict__ b3,
    const float* __restrict__ W4, const float* __restrict__ b4,
    const float* __restrict__ inv_denom,
    float* __restrict__ out)
{
    const int bs = blockIdx.x;           // b*S + s
    const int b = bs / Sc;
    const int tid = threadIdx.x;
    const int w = tid >> 6;              // wave 0..3
    const int lane = tid & 63;
    const int fk = lane < FKc ? lane : FKc - 1;
    const int f = fk / Kc;

    __shared__ float lds_id[Vc * FKc];   // 6000 f = 24KB
    __shared__ float lds_feat[Vc * Fc];  // 500 f
    __shared__ float lds_red[4][FKc];
    __shared__ float lds_gd[FKc];
    __shared__ float lds_h1[Kc];
    __shared__ float lds_h2[Fc];
    __shared__ float lds_logit[3];

    // stage inv_denom[b] as float4 (1500 x 16B, coalesced)
    const float4* idp = (const float4*)(inv_denom + (size_t)b * Vc * FKc);
    float4* ldp = (float4*)lds_id;
    for (int i = tid; i < Vc * FKc / 4; i += 256) ldp[i] = idp[i];
    // stage feat row
    const float* frow = feat + (size_t)bs * Vc * Fc;
    for (int i = tid; i < Vc * Fc; i += 256) lds_feat[i] = frow[i];

    float nr1, nr2, nr3, nt1, nt2, nt3;
    gauss_consts(mu_rho, sigma_rho, mu_theta, sigma_theta, fk,
                 nr1, nr2, nr3, nt1, nt2, nt3);

    __syncthreads();

    const size_t base_sv = (size_t)bs * Vc + w * VG;
    float acc = 0.0f;
#pragma unroll
    for (int vi = 0; vi < VG; ++vi) {
        const int v = w * VG + vi;
        float r = rho[base_sv + vi];     // wave-uniform
        float t = theta[base_sv + vi];
        float m = mask[base_sv + vi];
        float id = lds_id[v * FKc + fk];
        float fv = lds_feat[v * Fc + f];
        float ar = __fmaf_rn(__fmaf_rn(nr1, r, nr2), r, nr3);
        float at = __fmaf_rn(__fmaf_rn(nt1, t, nt2), t, nt3 + ar);
        acc = __fmaf_rn(__expf(at) * m * id, fv, acc);
    }
    if (lane < FKc) lds_red[w][lane] = acc;
    __syncthreads();

    // desc + conv per (f,j)
    if (tid < FKc) {
        float d0 = lds_red[0][tid] + lds_red[1][tid] +
                   lds_red[2][tid] + lds_red[3][tid];
        lds_gd[tid] = d0;                // temporarily desc
    }
    __syncthreads();
    float gd_val = 0.0f;
    if (tid < FKc) {
        const int ff = tid / Kc, j = tid % Kc;
        float sum = bc[tid];
#pragma unroll
        for (int k = 0; k < Kc; ++k)
            sum = __fmaf_rn(lds_gd[ff * Kc + k],
                            Wc[ff * Kc * Kc + k * Kc + j], sum);
        gd_val = fmaxf(sum, 0.0f);
    }
    __syncthreads();
    if (tid < FKc) lds_gd[tid] = gd_val;
    __syncthreads();

    // h1 = relu(gd @ W2 + b2)  (60 -> 12)
    if (tid < Kc) {
        float sum = b2[tid];
#pragma unroll
        for (int i = 0; i < FKc; ++i)
            sum = __fmaf_rn(lds_gd[i], W2[i * Kc + tid], sum);
        lds_h1[tid] = fmaxf(sum, 0.0f);
    }
    __syncthreads();

    // h2 = relu(h1 @ W3 + b3)  (12 -> 5)
    if (tid < Fc) {
        float sum = b3[tid];
#pragma unroll
        for (int i = 0; i < Kc; ++i)
            sum = __fmaf_rn(lds_h1[i], W3[i * Fc + tid], sum);
        lds_h2[tid] = fmaxf(sum, 0.0f);
    }
    __syncthreads();

    // logits (5 -> 3)
    if (tid < 3) {
        float sum = b4[tid];
#pragma unroll
        for (int i = 0; i < Fc; ++i)
            sum = __fmaf_rn(lds_h2[i], W4[i * 3 + tid], sum);
        lds_logit[tid] = sum;
    }
    __syncthreads();

    if (tid == 0) {
        float l0 = lds_logit[0], l1 = lds_logit[1], l2 = lds_logit[2];
        float mx = fmaxf(l0, fmaxf(l1, l2));
        float e0 = __expf(l0 - mx), e1 = __expf(l1 - mx), e2 = __expf(l2 - mx);
        float inv = 1.0f / (e0 + e1 + e2);
        out[(size_t)bs * 3 + 0] = e0 * inv;
        out[(size_t)bs * 3 + 1] = e1 * inv;
        out[(size_t)bs * 3 + 2] = e2 * inv;
    }
}

extern "C" void kernel_launch(void* const* d_in, const int* in_sizes, int n_in,
                              void* d_out, int out_size, void* d_ws, size_t ws_size,
                              hipStream_t stream) {
    const float* feat     = (const float*)d_in[0];
    const float* rho      = (const float*)d_in[1];
    const float* theta    = (const float*)d_in[2];
    const float* mask     = (const float*)d_in[3];
    const float* mu_rho   = (const float*)d_in[4];
    const float* sig_rho  = (const float*)d_in[5];
    const float* mu_theta = (const float*)d_in[6];
    const float* sig_th   = (const float*)d_in[7];
    const float* Wc       = (const float*)d_in[8];
    const float* bc       = (const float*)d_in[9];
    const float* W2       = (const float*)d_in[10];
    const float* b2       = (const float*)d_in[11];
    const float* W3       = (const float*)d_in[12];
    const float* b3       = (const float*)d_in[13];
    const float* W4       = (const float*)d_in[14];
    const float* b4       = (const float*)d_in[15];

    // workspace: inv_denom (48000 f = 192KB) then partials (SCH * 192KB)
    float* inv_denom = (float*)d_ws;
    const size_t inv_bytes = (size_t)NDEN * 4;
    size_t rem = ws_size > inv_bytes ? ws_size - inv_bytes : 0;
    int SCH = (int)(rem / inv_bytes);
    if (SCH > 50) SCH = 50;
    float* partial;
    if (SCH < 1) { SCH = 1; partial = inv_denom; }   // in-place fallback
    else partial = inv_denom + NDEN;
    const int chunk = (Sc + SCH - 1) / SCH;

    k_denom_partial<<<dim3(SCH, Bc, 4), 64, 0, stream>>>(
        rho, theta, mask, mu_rho, sig_rho, mu_theta, sig_th, partial, chunk);

    k_inv<<<(NDEN + 255) / 256, 256, 0, stream>>>(partial, inv_denom, SCH);

    k_main<<<Bc * Sc, 256, 0, stream>>>(
        feat, rho, theta, mask, mu_rho, sig_rho, mu_theta, sig_th,
        Wc, bc, W2, b2, W3, b3, W4, b4, inv_denom, (float*)d_out);
}

// Round 4
// 126.810 us; speedup vs baseline: 1.4882x; 1.1090x over previous
//
#include <hip/hip_runtime.h>
#include <math.h>

namespace {
constexpr int Bc = 8, Sc = 500, Vc = 100, Fc = 5, Kc = 12, FKc = 60;
constexpr int BV = Bc * Vc;          // 800
constexpr int NDEN = BV * FKc;       // 48000
constexpr int VG = 25;               // v's per block-z in k_denom
constexpr float EPSc = 1e-5f;
}

// -(x-mu)^2/(sig^2+EPS) = (n1*x + n2)*x + n3  (2 FMAs)
__device__ __forceinline__ void gauss_consts(
    const float* __restrict__ mu_rho, const float* __restrict__ sigma_rho,
    const float* __restrict__ mu_theta, const float* __restrict__ sigma_theta,
    int fk,
    float& nr1, float& nr2, float& nr3,
    float& nt1, float& nt2, float& nt3)
{
    float mr = mu_rho[fk],  sr = sigma_rho[fk];
    float mt = mu_theta[fk], st = sigma_theta[fk];
    float isr = 1.0f / (sr * sr + EPSc);
    float ist = 1.0f / (st * st + EPSc);
    nr1 = -isr; nr2 = 2.0f * isr * mr; nr3 = -(isr * mr) * mr;
    nt1 = -ist; nt2 = 2.0f * ist * mt; nt3 = -(ist * mt) * mt;
}

// Denominator partials. Grid (SCH, B, 4): block = (s-chunk, batch, v-group).
// Lane = fk; 25 register accumulators; contiguous (s,v) walk.
// partial[c][b][v][fk] flat = c*NDEN + (b*V+v)*60 + fk
__global__ __launch_bounds__(64) void k_denom_partial(
    const float* __restrict__ rho, const float* __restrict__ theta,
    const float* __restrict__ mask,
    const float* __restrict__ mu_rho, const float* __restrict__ sigma_rho,
    const float* __restrict__ mu_theta, const float* __restrict__ sigma_theta,
    float* __restrict__ partial, int chunk)
{
    const int c  = blockIdx.x;
    const int b  = blockIdx.y;
    const int wg = blockIdx.z;           // 0..3
    const int lane = threadIdx.x;
    const int fk = lane < FKc ? lane : FKc - 1;
    const int v0 = wg * VG;

    float nr1, nr2, nr3, nt1, nt2, nt3;
    gauss_consts(mu_rho, sigma_rho, mu_theta, sigma_theta, fk,
                 nr1, nr2, nr3, nt1, nt2, nt3);

    const int s0 = c * chunk;
    const int s1 = min(Sc, s0 + chunk);

    float acc[VG];
#pragma unroll
    for (int i = 0; i < VG; ++i) acc[i] = 0.0f;

    const size_t base = (size_t)b * Sc * Vc + v0;
    for (int s = s0; s < s1; ++s) {
        const float* rp = rho   + base + (size_t)s * Vc;
        const float* tp = theta + base + (size_t)s * Vc;
        const float* mp = mask  + base + (size_t)s * Vc;
#pragma unroll
        for (int vi = 0; vi < VG; ++vi) {
            float r = rp[vi], t = tp[vi], m = mp[vi];   // wave-uniform
            float ar = __fmaf_rn(__fmaf_rn(nr1, r, nr2), r, nr3);
            float at = __fmaf_rn(__fmaf_rn(nt1, t, nt2), t, nt3 + ar);
            acc[vi] = __fmaf_rn(__expf(at), m, acc[vi]);
        }
    }

    float* pp = partial + (size_t)c * NDEN + ((size_t)b * Vc + v0) * FKc;
    if (lane < FKc) {
#pragma unroll
        for (int vi = 0; vi < VG; ++vi)
            pp[(size_t)vi * FKc + lane] = acc[vi];      // coalesced
    }
}

// inv_denom[i] = 1/(sum_c partial[c][i] + EPS)
__global__ __launch_bounds__(256) void k_inv(
    const float* __restrict__ partial, float* __restrict__ inv_denom, int SCH)
{
    const int i = blockIdx.x * 256 + threadIdx.x;
    if (i >= NDEN) return;
    float s = 0.0f;
#pragma unroll 4
    for (int c = 0; c < SCH; ++c)
        s += partial[(size_t)c * NDEN + i];             // coalesced
    inv_denom[i] = 1.0f / (s + EPSc);
}

// Main: ONE WAVE per (b,s). Lane = fk owns desc[fk] over all 100 v.
// Row data + Wc/W2 staged in LDS; inv_denom read as coalesced L2-hot
// 240B loads in the unrolled v-loop. Tail runs in-wave (cheap barriers).
__global__ __launch_bounds__(64) void k_main(
    const float* __restrict__ feat, const float* __restrict__ rho,
    const float* __restrict__ theta, const float* __restrict__ mask,
    const float* __restrict__ mu_rho, const float* __restrict__ sigma_rho,
    const float* __restrict__ mu_theta, const float* __restrict__ sigma_theta,
    const float* __restrict__ Wc, const float* __restrict__ bc,
    const float* __restrict__ W2, const float* __restrict__ b2,
    const float* __restrict__ W3, const float* __restrict__ b3,
    const float* __restrict__ W4, const float* __restrict__ b4,
    const float* __restrict__ inv_denom,
    float* __restrict__ out)
{
    const int bs = blockIdx.x;           // b*S + s
    const int b = bs / Sc;
    const int lane = threadIdx.x;        // 0..63
    const int fk = lane < FKc ? lane : FKc - 1;
    const int f = fk / Kc;

    __shared__ float lds_feat[Vc * Fc];  // 500
    __shared__ float lds_r[Vc];          // 100
    __shared__ float lds_t[Vc];
    __shared__ float lds_m[Vc];
    __shared__ float lds_wc[Fc * Kc * Kc]; // 720
    __shared__ float lds_w2[FKc * Kc];     // 720
    __shared__ float lds_desc[FKc];
    __shared__ float lds_gd[FKc];
    __shared__ float lds_h1[Kc];
    __shared__ float lds_h2[Fc];
    __shared__ float lds_logit[3];

    // --- staging (all bases 16B-aligned) ---
    {
        const float4* s_f = (const float4*)(feat + (size_t)bs * Vc * Fc);
        float4* d_f = (float4*)lds_feat;
#pragma unroll
        for (int i = lane; i < Vc * Fc / 4; i += 64) d_f[i] = s_f[i];

        const float4* s_r = (const float4*)(rho   + (size_t)bs * Vc);
        const float4* s_t = (const float4*)(theta + (size_t)bs * Vc);
        const float4* s_m = (const float4*)(mask  + (size_t)bs * Vc);
        if (lane < Vc / 4) {
            ((float4*)lds_r)[lane] = s_r[lane];
            ((float4*)lds_t)[lane] = s_t[lane];
            ((float4*)lds_m)[lane] = s_m[lane];
        }
        const float4* s_wc = (const float4*)Wc;
        const float4* s_w2 = (const float4*)W2;
        float4* d_wc = (float4*)lds_wc;
        float4* d_w2 = (float4*)lds_w2;
#pragma unroll
        for (int i = lane; i < Fc * Kc * Kc / 4; i += 64) {
            d_wc[i] = s_wc[i];
            d_w2[i] = s_w2[i];
        }
    }

    float nr1, nr2, nr3, nt1, nt2, nt3;
    gauss_consts(mu_rho, sigma_rho, mu_theta, sigma_theta, fk,
                 nr1, nr2, nr3, nt1, nt2, nt3);

    __syncthreads();   // single wave: near-free

    const size_t base_bv = (size_t)b * Vc;
    float acc = 0.0f;
#pragma unroll 10
    for (int v = 0; v < Vc; ++v) {
        float id = inv_denom[(base_bv + v) * FKc + fk];  // coalesced, L2-hot
        float r = lds_r[v];                              // broadcast
        float t = lds_t[v];
        float m = lds_m[v];
        float fv = lds_feat[v * Fc + f];
        float ar = __fmaf_rn(__fmaf_rn(nr1, r, nr2), r, nr3);
        float at = __fmaf_rn(__fmaf_rn(nt1, t, nt2), t, nt3 + ar);
        acc = __fmaf_rn(__expf(at) * m * id, fv, acc);
    }
    if (lane < FKc) lds_desc[lane] = acc;
    __syncthreads();

    // conv per (f,j): relu(sum_k desc[f,k]*Wc[f,k,j] + bc[f,j])
    if (lane < FKc) {
        const int ff = lane / Kc, j = lane % Kc;
        float sum = bc[lane];
#pragma unroll
        for (int k = 0; k < Kc; ++k)
            sum = __fmaf_rn(lds_desc[ff * Kc + k],
                            lds_wc[ff * Kc * Kc + k * Kc + j], sum);
        lds_gd[lane] = fmaxf(sum, 0.0f);
    }
    __syncthreads();

    // h1 = relu(gd @ W2 + b2)  (60 -> 12)
    if (lane < Kc) {
        float sum = b2[lane];
#pragma unroll
        for (int i = 0; i < FKc; ++i)
            sum = __fmaf_rn(lds_gd[i], lds_w2[i * Kc + lane], sum);
        lds_h1[lane] = fmaxf(sum, 0.0f);
    }
    __syncthreads();

    // h2 = relu(h1 @ W3 + b3)  (12 -> 5)
    if (lane < Fc) {
        float sum = b3[lane];
#pragma unroll
        for (int i = 0; i < Kc; ++i)
            sum = __fmaf_rn(lds_h1[i], W3[i * Fc + lane], sum);
        lds_h2[lane] = fmaxf(sum, 0.0f);
    }
    __syncthreads();

    // logits (5 -> 3)
    if (lane < 3) {
        float sum = b4[lane];
#pragma unroll
        for (int i = 0; i < Fc; ++i)
            sum = __fmaf_rn(lds_h2[i], W4[i * 3 + lane], sum);
        lds_logit[lane] = sum;
    }
    __syncthreads();

    if (lane < 3) {
        float l0 = lds_logit[0], l1 = lds_logit[1], l2 = lds_logit[2];
        float mx = fmaxf(l0, fmaxf(l1, l2));
        float e0 = __expf(l0 - mx), e1 = __expf(l1 - mx), e2 = __expf(l2 - mx);
        float inv = 1.0f / (e0 + e1 + e2);
        float mine = lane == 0 ? e0 : (lane == 1 ? e1 : e2);
        out[(size_t)bs * 3 + lane] = mine * inv;
    }
}

extern "C" void kernel_launch(void* const* d_in, const int* in_sizes, int n_in,
                              void* d_out, int out_size, void* d_ws, size_t ws_size,
                              hipStream_t stream) {
    const float* feat     = (const float*)d_in[0];
    const float* rho      = (const float*)d_in[1];
    const float* theta    = (const float*)d_in[2];
    const float* mask     = (const float*)d_in[3];
    const float* mu_rho   = (const float*)d_in[4];
    const float* sig_rho  = (const float*)d_in[5];
    const float* mu_theta = (const float*)d_in[6];
    const float* sig_th   = (const float*)d_in[7];
    const float* Wc       = (const float*)d_in[8];
    const float* bc       = (const float*)d_in[9];
    const float* W2       = (const float*)d_in[10];
    const float* b2       = (const float*)d_in[11];
    const float* W3       = (const float*)d_in[12];
    const float* b3       = (const float*)d_in[13];
    const float* W4       = (const float*)d_in[14];
    const float* b4       = (const float*)d_in[15];

    // workspace: inv_denom (48000 f = 192KB) then partials (SCH * 192KB)
    float* inv_denom = (float*)d_ws;
    const size_t inv_bytes = (size_t)NDEN * 4;
    size_t rem = ws_size > inv_bytes ? ws_size - inv_bytes : 0;
    int SCH = (int)(rem / inv_bytes);
    if (SCH > 100) SCH = 100;       // chunk = 5 exactly
    float* partial;
    if (SCH < 1) { SCH = 1; partial = inv_denom; }   // in-place fallback
    else partial = inv_denom + NDEN;
    const int chunk = (Sc + SCH - 1) / SCH;

    k_denom_partial<<<dim3(SCH, Bc, 4), 64, 0, stream>>>(
        rho, theta, mask, mu_rho, sig_rho, mu_theta, sig_th, partial, chunk);

    k_inv<<<(NDEN + 255) / 256, 256, 0, stream>>>(partial, inv_denom, SCH);

    k_main<<<Bc * Sc, 64, 0, stream>>>(
        feat, rho, theta, mask, mu_rho, sig_rho, mu_theta, sig_th,
        Wc, bc, W2, b2, W3, b3, W4, b4, inv_denom, (float*)d_out);
}

// Round 6
// 123.978 us; speedup vs baseline: 1.5222x; 1.0228x over previous
//
#include <hip/hip_runtime.h>
#include <math.h>

namespace {
constexpr int Bc = 8, Sc = 500, Vc = 100, Fc = 5, Kc = 12, FKc = 60;
constexpr float EPSc = 1e-5f;
}

// -(x-mu)^2/(sig^2+EPS) = (n1*x + n2)*x + n3  (2 FMAs)
__device__ __forceinline__ void gauss_consts(
    const float* __restrict__ mu_rho, const float* __restrict__ sigma_rho,
    const float* __restrict__ mu_theta, const float* __restrict__ sigma_theta,
    int fk,
    float& nr1, float& nr2, float& nr3,
    float& nt1, float& nt2, float& nt3)
{
    float mr = mu_rho[fk],  sr = sigma_rho[fk];
    float mt = mu_theta[fk], st = sigma_theta[fk];
    float isr = 1.0f / (sr * sr + EPSc);
    float ist = 1.0f / (st * st + EPSc);
    nr1 = -isr; nr2 = 2.0f * isr * mr; nr3 = -(isr * mr) * mr;
    nt1 = -ist; nt2 = 2.0f * ist * mt; nt3 = -(ist * mt) * mt;
}

// Denominator in ONE kernel: block = (b,v), 128 threads = 2 waves.
// Wave w sums its 250-s half for all 60 fk (lane = fk); one LDS exchange;
// writes inv_denom[(b*V+v)*60 + fk] = 1/(sum + EPS) directly.
// All rho/theta/mask addresses are blockIdx+loop-derived -> wave-uniform.
__global__ __launch_bounds__(128) void k_denom2(
    const float* __restrict__ rho, const float* __restrict__ theta,
    const float* __restrict__ mask,
    const float* __restrict__ mu_rho, const float* __restrict__ sigma_rho,
    const float* __restrict__ mu_theta, const float* __restrict__ sigma_theta,
    float* __restrict__ inv_denom)
{
    const int bv = blockIdx.x;            // b*V + v
    const int b = bv / Vc, v = bv % Vc;
    const int w = threadIdx.x >> 6;       // s-half 0/1
    const int lane = threadIdx.x & 63;
    const int fk = lane < FKc ? lane : FKc - 1;

    float nr1, nr2, nr3, nt1, nt2, nt3;
    gauss_consts(mu_rho, sigma_rho, mu_theta, sigma_theta, fk,
                 nr1, nr2, nr3, nt1, nt2, nt3);

    const size_t base = (size_t)b * Sc * Vc + v;
    const int s0 = w * (Sc / 2);

    // 5 accumulators for ILP; 250 = 50 * 5
    float a0 = 0.f, a1 = 0.f, a2 = 0.f, a3 = 0.f, a4 = 0.f;
    for (int i = 0; i < Sc / 2; i += 5) {
        const size_t p = base + (size_t)(s0 + i) * Vc;
#define GSTEP(J, ACC)                                                        \
        {                                                                    \
            float r = rho[p + (size_t)(J) * Vc];                             \
            float t = theta[p + (size_t)(J) * Vc];                           \
            float m = mask[p + (size_t)(J) * Vc];                            \
            float ar = __fmaf_rn(__fmaf_rn(nr1, r, nr2), r, nr3);            \
            float at = __fmaf_rn(__fmaf_rn(nt1, t, nt2), t, nt3 + ar);       \
            ACC = __fmaf_rn(__expf(at), m, ACC);                             \
        }
        GSTEP(0, a0) GSTEP(1, a1) GSTEP(2, a2) GSTEP(3, a3) GSTEP(4, a4)
#undef GSTEP
    }
    float acc = ((a0 + a1) + (a2 + a3)) + a4;

    __shared__ float red[2][64];
    red[w][lane] = acc;
    __syncthreads();
    if (w == 0 && lane < FKc)
        inv_denom[(size_t)bv * FKc + lane] =
            1.0f / (red[0][lane] + red[1][lane] + EPSc);
}

// Main: ONE WAVE per (b,s). Lane = fk owns desc[fk] over all 100 v.
// Row data staged in LDS; inv_denom / weights read from L2 directly.
__global__ __launch_bounds__(64) void k_main(
    const float* __restrict__ feat, const float* __restrict__ rho,
    const float* __restrict__ theta, const float* __restrict__ mask,
    const float* __restrict__ mu_rho, const float* __restrict__ sigma_rho,
    const float* __restrict__ mu_theta, const float* __restrict__ sigma_theta,
    const float* __restrict__ Wc, const float* __restrict__ bc,
    const float* __restrict__ W2, const float* __restrict__ b2,
    const float* __restrict__ W3, const float* __restrict__ b3,
    const float* __restrict__ W4, const float* __restrict__ b4,
    const float* __restrict__ inv_denom,
    float* __restrict__ out)
{
    const int bs = blockIdx.x;           // b*S + s
    const int b = bs / Sc;
    const int lane = threadIdx.x;        // 0..63
    const int fk = lane < FKc ? lane : FKc - 1;
    const int f = fk / Kc;

    __shared__ float lds_feat[Vc * Fc];  // 500
    __shared__ float lds_r[Vc];
    __shared__ float lds_t[Vc];
    __shared__ float lds_m[Vc];
    __shared__ float lds_desc[FKc];
    __shared__ float lds_gd[FKc];
    __shared__ float lds_h1[Kc];
    __shared__ float lds_h2[Fc];
    __shared__ float lds_logit[3];

    // --- stage per-row data (16B-aligned bases) ---
    {
        const float4* s_f = (const float4*)(feat + (size_t)bs * Vc * Fc);
        float4* d_f = (float4*)lds_feat;
#pragma unroll
        for (int i = lane; i < Vc * Fc / 4; i += 64) d_f[i] = s_f[i];

        const float4* s_r = (const float4*)(rho   + (size_t)bs * Vc);
        const float4* s_t = (const float4*)(theta + (size_t)bs * Vc);
        const float4* s_m = (const float4*)(mask  + (size_t)bs * Vc);
        if (lane < Vc / 4) {
            ((float4*)lds_r)[lane] = s_r[lane];
            ((float4*)lds_t)[lane] = s_t[lane];
            ((float4*)lds_m)[lane] = s_m[lane];
        }
    }

    float nr1, nr2, nr3, nt1, nt2, nt3;
    gauss_consts(mu_rho, sigma_rho, mu_theta, sigma_theta, fk,
                 nr1, nr2, nr3, nt1, nt2, nt3);

    __syncthreads();

    const size_t base_bv = (size_t)b * Vc;
    float acc = 0.0f;
#pragma unroll 10
    for (int v = 0; v < Vc; ++v) {
        float id = inv_denom[(base_bv + v) * FKc + fk];  // coalesced, L2-hot
        float r = lds_r[v];                              // broadcast
        float t = lds_t[v];
        float m = lds_m[v];
        float fv = lds_feat[v * Fc + f];
        float ar = __fmaf_rn(__fmaf_rn(nr1, r, nr2), r, nr3);
        float at = __fmaf_rn(__fmaf_rn(nt1, t, nt2), t, nt3 + ar);
        acc = __fmaf_rn(__expf(at) * m * id, fv, acc);
    }
    if (lane < FKc) lds_desc[lane] = acc;
    __syncthreads();

    // conv per (f,j): relu(sum_k desc[f,k]*Wc[f,k,j] + bc[f,j])  (L2-hot Wc)
    if (lane < FKc) {
        const int ff = lane / Kc, j = lane % Kc;
        float sum = bc[lane];
#pragma unroll
        for (int k = 0; k < Kc; ++k)
            sum = __fmaf_rn(lds_desc[ff * Kc + k],
                            Wc[ff * Kc * Kc + k * Kc + j], sum);
        lds_gd[lane] = fmaxf(sum, 0.0f);
    }
    __syncthreads();

    // h1 = relu(gd @ W2 + b2)  (60 -> 12)
    if (lane < Kc) {
        float sum = b2[lane];
#pragma unroll
        for (int i = 0; i < FKc; ++i)
            sum = __fmaf_rn(lds_gd[i], W2[i * Kc + lane], sum);
        lds_h1[lane] = fmaxf(sum, 0.0f);
    }
    __syncthreads();

    // h2 = relu(h1 @ W3 + b3)  (12 -> 5)
    if (lane < Fc) {
        float sum = b3[lane];
#pragma unroll
        for (int i = 0; i < Kc; ++i)
            sum = __fmaf_rn(lds_h1[i], W3[i * Fc + lane], sum);
        lds_h2[lane] = fmaxf(sum, 0.0f);
    }
    __syncthreads();

    // logits (5 -> 3)
    if (lane < 3) {
        float sum = b4[lane];
#pragma unroll
        for (int i = 0; i < Fc; ++i)
            sum = __fmaf_rn(lds_h2[i], W4[i * 3 + lane], sum);
        lds_logit[lane] = sum;
    }
    __syncthreads();

    if (lane < 3) {
        float l0 = lds_logit[0], l1 = lds_logit[1], l2 = lds_logit[2];
        float mx = fmaxf(l0, fmaxf(l1, l2));
        float e0 = __expf(l0 - mx), e1 = __expf(l1 - mx), e2 = __expf(l2 - mx);
        float inv = 1.0f / (e0 + e1 + e2);
        float mine = lane == 0 ? e0 : (lane == 1 ? e1 : e2);
        out[(size_t)bs * 3 + lane] = mine * inv;
    }
}

extern "C" void kernel_launch(void* const* d_in, const int* in_sizes, int n_in,
                              void* d_out, int out_size, void* d_ws, size_t ws_size,
                              hipStream_t stream) {
    const float* feat     = (const float*)d_in[0];
    const float* rho      = (const float*)d_in[1];
    const float* theta    = (const float*)d_in[2];
    const float* mask     = (const float*)d_in[3];
    const float* mu_rho   = (const float*)d_in[4];
    const float* sig_rho  = (const float*)d_in[5];
    const float* mu_theta = (const float*)d_in[6];
    const float* sig_th   = (const float*)d_in[7];
    const float* Wc       = (const float*)d_in[8];
    const float* bc       = (const float*)d_in[9];
    const float* W2       = (const float*)d_in[10];
    const float* b2       = (const float*)d_in[11];
    const float* W3       = (const float*)d_in[12];
    const float* b3       = (const float*)d_in[13];
    const float* W4       = (const float*)d_in[14];
    const float* b4       = (const float*)d_in[15];

    float* inv_denom = (float*)d_ws;     // 48000 floats = 192 KB

    k_denom2<<<Bc * Vc, 128, 0, stream>>>(
        rho, theta, mask, mu_rho, sig_rho, mu_theta, sig_th, inv_denom);

    k_main<<<Bc * Sc, 64, 0, stream>>>(
        feat, rho, theta, mask, mu_rho, sig_rho, mu_theta, sig_th,
        Wc, bc, W2, b2, W3, b3, W4, b4, inv_denom, (float*)d_out);
}